// Round 1
// baseline (3559.595 us; speedup 1.0000x reference)
//
#include <hip/hip_runtime.h>
#include <hip/hip_bf16.h>

#define N_NODES 100000
#define N_EDGES 1600000
#define CH 128
#define N_REL 8

using frag_ab = __attribute__((ext_vector_type(8))) short;  // 8 bf16
using frag_cd = __attribute__((ext_vector_type(4))) float;  // 4 fp32

__device__ __forceinline__ short f2bs(float f) {
    union { __hip_bfloat16 h; short s; } u;
    u.h = __float2bfloat16(f);
    return u.s;
}

// ---- count edges per (relation, dst) segment ----
__global__ void count_kernel(const int* __restrict__ ei, const int* __restrict__ et,
                             int* __restrict__ cnt) {
    int e = blockIdx.x * 256 + threadIdx.x;
    if (e < N_EDGES) {
        int dst = ei[N_EDGES + e];
        int r = et[e];
        atomicAdd(&cnt[r * N_NODES + dst], 1);
    }
}

// ---- scatter-add x[src] into sums[dst] for edges of type `rel` ----
// 32-lane group per edge, float4 per lane (128 ch)
__global__ void scatter_kernel(const int* __restrict__ ei, const int* __restrict__ et,
                               const float* __restrict__ x, float* __restrict__ sums,
                               int rel) {
    int gid = (blockIdx.x * 256 + threadIdx.x) >> 5;
    int lane = threadIdx.x & 31;
    int ngroups = gridDim.x * 8;
    for (int e = gid; e < N_EDGES; e += ngroups) {
        if (et[e] != rel) continue;
        int src = ei[e];
        int dst = ei[N_EDGES + e];
        float4 v = ((const float4*)(x + (size_t)src * CH))[lane];
        float* s = sums + (size_t)dst * CH + (size_t)lane * 4;
        atomicAdd(s + 0, v.x);
        atomicAdd(s + 1, v.y);
        atomicAdd(s + 2, v.z);
        atomicAdd(s + 3, v.w);
    }
}

// ---- out[N,128] (+)= scale(A[N,128]) @ B[128,128]  via bf16 MFMA ----
// cnt != nullptr: scale row i by 1/max(cnt[i],1) and accumulate (+=)
// cnt == nullptr: overwrite mode, adds bias[col]
// B fragments (all 128x128) preloaded into registers once per block.
__global__ __launch_bounds__(256, 2)
void gemm_kernel(const float* __restrict__ A, const float* __restrict__ B,
                 const float* __restrict__ bias, const int* __restrict__ cnt,
                 float* __restrict__ out, int accumulate) {
    const int wave = threadIdx.x >> 6;
    const int lane = threadIdx.x & 63;
    const int m16 = lane & 15;   // A row / B col / D col within 16-tile
    const int quad = lane >> 4;  // k sub-block for A/B frags; D row group

    // preload B fragments: bfrag[ks][ct]; B[k][n] with k = ks*32+quad*8+j, n = ct*16+m16
    frag_ab bfrag[4][8];
    #pragma unroll
    for (int ks = 0; ks < 4; ++ks) {
        const int kb = ks * 32 + quad * 8;
        #pragma unroll
        for (int ct = 0; ct < 8; ++ct) {
            const int col = ct * 16 + m16;
            frag_ab f;
            #pragma unroll
            for (int j = 0; j < 8; ++j)
                f[j] = f2bs(B[(size_t)(kb + j) * CH + col]);
            bfrag[ks][ct] = f;
        }
    }

    const int nstrips = (N_NODES + 63) / 64;  // 64 rows per block-strip (16/wave)
    for (int strip = blockIdx.x; strip < nstrips; strip += gridDim.x) {
        const int row = strip * 64 + wave * 16 + m16;
        const bool valid = row < N_NODES;
        float scale = 1.0f;
        if (cnt != nullptr && valid) {
            int c = cnt[row];
            if (c > 1) scale = 1.0f / (float)c;
        }
        const float4* arow = (const float4*)(A + (size_t)(valid ? row : 0) * CH);
        frag_cd acc[8];
        #pragma unroll
        for (int ct = 0; ct < 8; ++ct) acc[ct] = (frag_cd){0.f, 0.f, 0.f, 0.f};
        #pragma unroll
        for (int ks = 0; ks < 4; ++ks) {
            float4 a0 = arow[ks * 8 + quad * 2];
            float4 a1 = arow[ks * 8 + quad * 2 + 1];
            frag_ab af;
            af[0] = f2bs(a0.x * scale); af[1] = f2bs(a0.y * scale);
            af[2] = f2bs(a0.z * scale); af[3] = f2bs(a0.w * scale);
            af[4] = f2bs(a1.x * scale); af[5] = f2bs(a1.y * scale);
            af[6] = f2bs(a1.z * scale); af[7] = f2bs(a1.w * scale);
            #pragma unroll
            for (int ct = 0; ct < 8; ++ct)
                acc[ct] = __builtin_amdgcn_mfma_f32_16x16x32_bf16(af, bfrag[ks][ct], acc[ct], 0, 0, 0);
        }
        // D layout: row = quad*4 + rg, col = m16 (within 16x16 tile)
        const int obase = strip * 64 + wave * 16 + quad * 4;
        #pragma unroll
        for (int ct = 0; ct < 8; ++ct) {
            const int col = ct * 16 + m16;
            #pragma unroll
            for (int rg = 0; rg < 4; ++rg) {
                const int r = obase + rg;
                if (r < N_NODES) {
                    const size_t idx = (size_t)r * CH + col;
                    if (accumulate) out[idx] += acc[ct][rg];
                    else out[idx] = acc[ct][rg] + bias[col];
                }
            }
        }
    }
}

// ---- fallback: per-edge transform (slow but tiny workspace) ----
__global__ void edge_transform_kernel(const int* __restrict__ ei, const int* __restrict__ et,
                                      const float* __restrict__ x, const float* __restrict__ W,
                                      const int* __restrict__ cnt, float* __restrict__ out) {
    __shared__ float xs[CH];
    const int tid = threadIdx.x;
    for (int e = blockIdx.x; e < N_EDGES; e += gridDim.x) {
        const int src = ei[e];
        const int dst = ei[N_EDGES + e];
        const int r = et[e];
        __syncthreads();
        xs[tid] = x[(size_t)src * CH + tid];
        __syncthreads();
        const int c = cnt[r * N_NODES + dst];
        const float scale = (c > 1) ? (1.0f / (float)c) : 1.0f;
        const float* Wr = W + (size_t)r * CH * CH;
        float acc = 0.f;
        #pragma unroll 8
        for (int k = 0; k < CH; ++k) acc += xs[k] * Wr[(size_t)k * CH + tid];
        atomicAdd(&out[(size_t)dst * CH + tid], acc * scale);
    }
}

extern "C" void kernel_launch(void* const* d_in, const int* in_sizes, int n_in,
                              void* d_out, int out_size, void* d_ws, size_t ws_size,
                              hipStream_t stream) {
    const float* x    = (const float*)d_in[0];
    const int*   ei   = (const int*)d_in[1];   // [2, E]: row0=src, row1=dst
    const int*   et   = (const int*)d_in[2];   // [E]
    const float* W    = (const float*)d_in[3]; // [R,128,128]
    const float* root = (const float*)d_in[4]; // [128,128]
    const float* bias = (const float*)d_in[5]; // [128]
    float* out = (float*)d_out;

    const size_t cnt_bytes  = (size_t)N_REL * N_NODES * sizeof(int);   // 3.2 MB
    const size_t cnt_rsv    = (cnt_bytes + 511) & ~(size_t)511;
    const size_t sums_bytes = (size_t)N_NODES * CH * sizeof(float);    // 51.2 MB
    int*   cnt  = (int*)d_ws;
    float* sums = (float*)((char*)d_ws + cnt_rsv);

    // counts per (relation, dst)
    hipMemsetAsync(cnt, 0, cnt_bytes, stream);
    count_kernel<<<(N_EDGES + 255) / 256, 256, 0, stream>>>(ei, et, cnt);

    // out = x @ root + bias
    gemm_kernel<<<512, 256, 0, stream>>>(x, root, bias, nullptr, out, 0);

    if (ws_size >= cnt_rsv + sums_bytes) {
        // per-relation: sums = segment_sum(x[src]); out += (sums/max(cnt,1)) @ W_r
        for (int r = 0; r < N_REL; ++r) {
            hipMemsetAsync(sums, 0, sums_bytes, stream);
            scatter_kernel<<<6400, 256, 0, stream>>>(ei, et, x, sums, r);
            gemm_kernel<<<512, 256, 0, stream>>>(sums, W + (size_t)r * CH * CH,
                                                 nullptr, cnt + (size_t)r * N_NODES, out, 1);
        }
    } else {
        // tiny-workspace fallback: transform per edge, atomic into out
        edge_transform_kernel<<<65536, CH, 0, stream>>>(ei, et, x, W, cnt, out);
    }
}

// Round 2
// 870.125 us; speedup vs baseline: 4.0909x; 4.0909x over previous
//
#include <hip/hip_runtime.h>
#include <hip/hip_bf16.h>
#include <stdint.h>

#define N_NODES 100000
#define N_EDGES 1600000
#define CH 128
#define N_REL 8
#define N_PAD 100096   // N_NODES rounded up to multiple of 128 (GEMM strip pad)

using frag_ab = __attribute__((ext_vector_type(8))) short;  // 8 bf16
using frag_cd = __attribute__((ext_vector_type(4))) float;  // 4 fp32

__device__ __forceinline__ short f2bs(float f) {
    union { __hip_bfloat16 h; short s; } u;
    u.h = __float2bfloat16(f);
    return u.s;
}

__device__ __forceinline__ uint32_t pack2bf(float a, float b) {
    union { __hip_bfloat16 h; unsigned short s; } ua, ub;
    ua.h = __float2bfloat16(a); ub.h = __float2bfloat16(b);
    return (uint32_t)ua.s | ((uint32_t)ub.s << 16);
}

// ======================= FAST PATH (CSR, no value atomics) =======================

// count edges per dst
__global__ void count_dst_kernel(const int* __restrict__ ei, int* __restrict__ cnt) {
    int e = blockIdx.x * 256 + threadIdx.x;
    if (e < N_EDGES) atomicAdd(&cnt[ei[N_EDGES + e]], 1);
}

// exclusive scan of cnt_dst[100000] -> offs (and cursor copy). One block, 1024 threads.
__global__ void scan_kernel(const int* __restrict__ cnt, int* __restrict__ offs,
                            int* __restrict__ cursor) {
    __shared__ int tot[1024];
    const int t = threadIdx.x;
    const int CHUNK = (N_NODES + 1023) / 1024;  // 98
    const int base = t * CHUNK;
    int sum = 0;
    for (int i = 0; i < CHUNK; ++i) {
        int idx = base + i;
        if (idx < N_NODES) sum += cnt[idx];
    }
    tot[t] = sum;
    __syncthreads();
    // Hillis-Steele inclusive scan over 1024 totals
    for (int s = 1; s < 1024; s <<= 1) {
        int v = (t >= s) ? tot[t - s] : 0;
        __syncthreads();
        tot[t] += v;
        __syncthreads();
    }
    int run = (t == 0) ? 0 : tot[t - 1];  // exclusive base for this chunk
    for (int i = 0; i < CHUNK; ++i) {
        int idx = base + i;
        if (idx < N_NODES) {
            offs[idx] = run;
            cursor[idx] = run;
            run += cnt[idx];
        }
    }
    if (t == 1023) offs[N_NODES] = tot[1023];
}

// scatter edge (src, rel) packed into dst-sorted slots
__global__ void permute_kernel(const int* __restrict__ ei, const int* __restrict__ et,
                               int* __restrict__ cursor, int* __restrict__ perm) {
    int e = blockIdx.x * 256 + threadIdx.x;
    if (e < N_EDGES) {
        int dst = ei[N_EDGES + e];
        int src = ei[e];
        int r = et[e];
        int pos = atomicAdd(&cursor[dst], 1);
        perm[pos] = src | (r << 17);   // N_NODES < 2^17
    }
}

// wave per dst: gather x[src], per-relation fp32 sums + local counts, write bf16 means.
// sums layout: [rel][N_PAD][128] bf16
__global__ __launch_bounds__(256)
void aggregate_kernel(const int* __restrict__ offs, const int* __restrict__ perm,
                      const float* __restrict__ x, uint32_t* __restrict__ sums_u32) {
    const int dst = (blockIdx.x * 256 + threadIdx.x) >> 6;
    if (dst >= N_NODES) return;
    const int lane = threadIdx.x & 63;

    float2 acc[N_REL];
    int cr[N_REL];
#pragma unroll
    for (int r = 0; r < N_REL; ++r) { acc[r].x = 0.f; acc[r].y = 0.f; cr[r] = 0; }

    const int s = offs[dst], e = offs[dst + 1];
    for (int k = s; k < e; ++k) {
        int p = perm[k];                 // lane-uniform broadcast load
        int src = p & 0x1FFFF;
        int r = p >> 17;
        float2 v = *(const float2*)(x + (size_t)src * CH + lane * 2);
        switch (r) {                     // r is wave-uniform -> uniform branch
            case 0: acc[0].x += v.x; acc[0].y += v.y; cr[0]++; break;
            case 1: acc[1].x += v.x; acc[1].y += v.y; cr[1]++; break;
            case 2: acc[2].x += v.x; acc[2].y += v.y; cr[2]++; break;
            case 3: acc[3].x += v.x; acc[3].y += v.y; cr[3]++; break;
            case 4: acc[4].x += v.x; acc[4].y += v.y; cr[4]++; break;
            case 5: acc[5].x += v.x; acc[5].y += v.y; cr[5]++; break;
            case 6: acc[6].x += v.x; acc[6].y += v.y; cr[6]++; break;
            default: acc[7].x += v.x; acc[7].y += v.y; cr[7]++; break;
        }
    }
#pragma unroll
    for (int r = 0; r < N_REL; ++r) {
        float sc = (cr[r] > 1) ? (1.0f / (float)cr[r]) : 1.0f;
        sums_u32[((size_t)r * N_PAD + dst) * 64 + lane] = pack2bf(acc[r].x * sc, acc[r].y * sc);
    }
}

// x fp32 -> bf16 (flat copy of N*128 elements)
__global__ void xconv_kernel(const float* __restrict__ x, short* __restrict__ xb) {
    int g = blockIdx.x * 256 + threadIdx.x;       // one per 8 elements
    if (g >= N_NODES * CH / 8) return;
    const float4* xp = (const float4*)x;
    float4 a = xp[(size_t)g * 2], b = xp[(size_t)g * 2 + 1];
    frag_ab f;
    f[0] = f2bs(a.x); f[1] = f2bs(a.y); f[2] = f2bs(a.z); f[3] = f2bs(a.w);
    f[4] = f2bs(b.x); f[5] = f2bs(b.y); f[6] = f2bs(b.z); f[7] = f2bs(b.w);
    *(frag_ab*)(xb + (size_t)g * 8) = f;
}

// build swizzled bf16 B: Bsw[chunk][entry][8], entry = ((ks*4+quad)*8+ct)*16+m16
// chunk 0 = root, chunk c>=1 = W[c-1]; frag j -> B[ks*32+quad*8+j][ct*16+m16]
__global__ void bconv_kernel(const float* __restrict__ root, const float* __restrict__ W,
                             short* __restrict__ Bsw) {
    int g = blockIdx.x * 256 + threadIdx.x;
    if (g >= 9 * 2048) return;
    int chunk = g >> 11, entry = g & 2047;
    int m16 = entry & 15, ct = (entry >> 4) & 7, quad = (entry >> 7) & 3, ks = entry >> 9;
    const float* src = (chunk == 0) ? root : W + (size_t)(chunk - 1) * CH * CH;
    int col = ct * 16 + m16, kb = ks * 32 + quad * 8;
    frag_ab f;
#pragma unroll
    for (int j = 0; j < 8; ++j) f[j] = f2bs(src[(size_t)(kb + j) * CH + col]);
    *(frag_ab*)(Bsw + (size_t)g * 8) = f;
}

// out[N,128] = [x | mean_r] @ [root; W_0..W_7] + bias   (K = 1152 = 9 chunks of 128)
// block = 128 rows x 128 cols; 4 waves in 2x2 (each 64x64); B chunk staged in LDS.
__global__ __launch_bounds__(256, 2)
void gemm_fused(const short* __restrict__ xb, const short* __restrict__ sums,
                const short* __restrict__ Bsw, const float* __restrict__ bias,
                float* __restrict__ out) {
    __shared__ short bsh[2048 * 8];   // 32 KB
    const int tid = threadIdx.x;
    const int wave = tid >> 6, lane = tid & 63;
    const int m16 = lane & 15, quad = lane >> 4;
    const int wrow = wave >> 1, wcol = wave & 1;
    const long rowbase = (long)blockIdx.x * 128 + wrow * 64;

    float bcol[4];
#pragma unroll
    for (int ct = 0; ct < 4; ++ct) bcol[ct] = bias[wcol * 64 + ct * 16 + m16];

    frag_cd acc[4][4];
#pragma unroll
    for (int mt = 0; mt < 4; ++mt)
#pragma unroll
        for (int ct = 0; ct < 4; ++ct) acc[mt][ct] = (frag_cd){0.f, 0.f, 0.f, 0.f};

    for (int chunk = 0; chunk < 9; ++chunk) {
        __syncthreads();
        {   // stage 32 KB B chunk: 2048 float4s, 8 per thread, contiguous
            const float4* src = (const float4*)(Bsw + (size_t)chunk * 2048 * 8);
            float4* dst = (float4*)bsh;
#pragma unroll
            for (int i = 0; i < 8; ++i) dst[tid + 256 * i] = src[tid + 256 * i];
        }
        __syncthreads();
        const short* ab = (chunk == 0) ? xb : sums + (size_t)(chunk - 1) * N_PAD * CH;
#pragma unroll
        for (int ks = 0; ks < 4; ++ks) {
            frag_ab af[4];
#pragma unroll
            for (int mt = 0; mt < 4; ++mt)
                af[mt] = *(const frag_ab*)(ab + (rowbase + mt * 16 + m16) * CH + ks * 32 + quad * 8);
#pragma unroll
            for (int ct = 0; ct < 4; ++ct) {
                frag_ab bf = *(const frag_ab*)(bsh + ((((ks * 4 + quad) * 8) + wcol * 4 + ct) * 16 + m16) * 8);
#pragma unroll
                for (int mt = 0; mt < 4; ++mt)
                    acc[mt][ct] = __builtin_amdgcn_mfma_f32_16x16x32_bf16(af[mt], bf, acc[mt][ct], 0, 0, 0);
            }
        }
    }
    // D layout: row = quad*4 + rg, col = m16 (per 16x16 tile)
#pragma unroll
    for (int mt = 0; mt < 4; ++mt) {
#pragma unroll
        for (int ct = 0; ct < 4; ++ct) {
            const long row0 = rowbase + mt * 16 + quad * 4;
            const int col = wcol * 64 + ct * 16 + m16;
#pragma unroll
            for (int rg = 0; rg < 4; ++rg) {
                long r = row0 + rg;
                if (r < N_NODES) out[r * CH + col] = acc[mt][ct][rg] + bcol[ct];
            }
        }
    }
}

// ======================= FALLBACK PATHS (round-1 code) =======================

__global__ void count_rd_kernel(const int* __restrict__ ei, const int* __restrict__ et,
                                int* __restrict__ cnt) {
    int e = blockIdx.x * 256 + threadIdx.x;
    if (e < N_EDGES) {
        int dst = ei[N_EDGES + e];
        int r = et[e];
        atomicAdd(&cnt[r * N_NODES + dst], 1);
    }
}

__global__ void scatter_kernel(const int* __restrict__ ei, const int* __restrict__ et,
                               const float* __restrict__ x, float* __restrict__ sums,
                               int rel) {
    int gid = (blockIdx.x * 256 + threadIdx.x) >> 5;
    int lane = threadIdx.x & 31;
    int ngroups = gridDim.x * 8;
    for (int e = gid; e < N_EDGES; e += ngroups) {
        if (et[e] != rel) continue;
        int src = ei[e];
        int dst = ei[N_EDGES + e];
        float4 v = ((const float4*)(x + (size_t)src * CH))[lane];
        float* s = sums + (size_t)dst * CH + (size_t)lane * 4;
        atomicAdd(s + 0, v.x);
        atomicAdd(s + 1, v.y);
        atomicAdd(s + 2, v.z);
        atomicAdd(s + 3, v.w);
    }
}

__global__ __launch_bounds__(256, 2)
void gemm_kernel(const float* __restrict__ A, const float* __restrict__ B,
                 const float* __restrict__ bias, const int* __restrict__ cnt,
                 float* __restrict__ out, int accumulate) {
    const int wave = threadIdx.x >> 6;
    const int lane = threadIdx.x & 63;
    const int m16 = lane & 15;
    const int quad = lane >> 4;

    frag_ab bfrag[4][8];
#pragma unroll
    for (int ks = 0; ks < 4; ++ks) {
        const int kb = ks * 32 + quad * 8;
#pragma unroll
        for (int ct = 0; ct < 8; ++ct) {
            const int col = ct * 16 + m16;
            frag_ab f;
#pragma unroll
            for (int j = 0; j < 8; ++j)
                f[j] = f2bs(B[(size_t)(kb + j) * CH + col]);
            bfrag[ks][ct] = f;
        }
    }

    const int nstrips = (N_NODES + 63) / 64;
    for (int strip = blockIdx.x; strip < nstrips; strip += gridDim.x) {
        const int row = strip * 64 + wave * 16 + m16;
        const bool valid = row < N_NODES;
        float scale = 1.0f;
        if (cnt != nullptr && valid) {
            int c = cnt[row];
            if (c > 1) scale = 1.0f / (float)c;
        }
        const float4* arow = (const float4*)(A + (size_t)(valid ? row : 0) * CH);
        frag_cd acc[8];
#pragma unroll
        for (int ct = 0; ct < 8; ++ct) acc[ct] = (frag_cd){0.f, 0.f, 0.f, 0.f};
#pragma unroll
        for (int ks = 0; ks < 4; ++ks) {
            float4 a0 = arow[ks * 8 + quad * 2];
            float4 a1 = arow[ks * 8 + quad * 2 + 1];
            frag_ab af;
            af[0] = f2bs(a0.x * scale); af[1] = f2bs(a0.y * scale);
            af[2] = f2bs(a0.z * scale); af[3] = f2bs(a0.w * scale);
            af[4] = f2bs(a1.x * scale); af[5] = f2bs(a1.y * scale);
            af[6] = f2bs(a1.z * scale); af[7] = f2bs(a1.w * scale);
#pragma unroll
            for (int ct = 0; ct < 8; ++ct)
                acc[ct] = __builtin_amdgcn_mfma_f32_16x16x32_bf16(af, bfrag[ks][ct], acc[ct], 0, 0, 0);
        }
        const int obase = strip * 64 + wave * 16 + quad * 4;
#pragma unroll
        for (int ct = 0; ct < 8; ++ct) {
            const int col = ct * 16 + m16;
#pragma unroll
            for (int rg = 0; rg < 4; ++rg) {
                const int r = obase + rg;
                if (r < N_NODES) {
                    const size_t idx = (size_t)r * CH + col;
                    if (accumulate) out[idx] += acc[ct][rg];
                    else out[idx] = acc[ct][rg] + bias[col];
                }
            }
        }
    }
}

__global__ void edge_transform_kernel(const int* __restrict__ ei, const int* __restrict__ et,
                                      const float* __restrict__ x, const float* __restrict__ W,
                                      const int* __restrict__ cnt, float* __restrict__ out) {
    __shared__ float xs[CH];
    const int tid = threadIdx.x;
    for (int e = blockIdx.x; e < N_EDGES; e += gridDim.x) {
        const int src = ei[e];
        const int dst = ei[N_EDGES + e];
        const int r = et[e];
        __syncthreads();
        xs[tid] = x[(size_t)src * CH + tid];
        __syncthreads();
        const int c = cnt[r * N_NODES + dst];
        const float scale = (c > 1) ? (1.0f / (float)c) : 1.0f;
        const float* Wr = W + (size_t)r * CH * CH;
        float acc = 0.f;
#pragma unroll 8
        for (int k = 0; k < CH; ++k) acc += xs[k] * Wr[(size_t)k * CH + tid];
        atomicAdd(&out[(size_t)dst * CH + tid], acc * scale);
    }
}

// ======================= launch =======================

static inline size_t al512(size_t x) { return (x + 511) & ~(size_t)511; }

extern "C" void kernel_launch(void* const* d_in, const int* in_sizes, int n_in,
                              void* d_out, int out_size, void* d_ws, size_t ws_size,
                              hipStream_t stream) {
    const float* x    = (const float*)d_in[0];
    const int*   ei   = (const int*)d_in[1];   // [2, E]: row0=src, row1=dst
    const int*   et   = (const int*)d_in[2];   // [E]
    const float* W    = (const float*)d_in[3]; // [R,128,128]
    const float* root = (const float*)d_in[4]; // [128,128]
    const float* bias = (const float*)d_in[5]; // [128]
    float* out = (float*)d_out;

    // ---- fast-path workspace layout ----
    size_t o = 0;
    const size_t o_cnt  = o; o += al512((size_t)N_NODES * 4);
    const size_t o_offs = o; o += al512((size_t)(N_NODES + 1) * 4);
    const size_t o_cur  = o; o += al512((size_t)N_NODES * 4);
    const size_t o_perm = o; o += al512((size_t)N_EDGES * 4);
    const size_t o_bsw  = o; o += al512((size_t)9 * 2048 * 16);
    const size_t o_xb   = o; o += al512((size_t)N_PAD * CH * 2);
    const size_t o_sums = o; o += al512((size_t)N_REL * N_PAD * CH * 2);
    const size_t need_fast = o;

    const size_t cnt_bytes  = (size_t)N_REL * N_NODES * sizeof(int);
    const size_t cnt_rsv    = al512(cnt_bytes);
    const size_t sums51     = (size_t)N_NODES * CH * sizeof(float);

    if (ws_size >= need_fast) {
        char* ws = (char*)d_ws;
        int*      cnt    = (int*)(ws + o_cnt);
        int*      offs   = (int*)(ws + o_offs);
        int*      cursor = (int*)(ws + o_cur);
        int*      perm   = (int*)(ws + o_perm);
        short*    Bsw    = (short*)(ws + o_bsw);
        short*    xb     = (short*)(ws + o_xb);
        short*    sums   = (short*)(ws + o_sums);

        hipMemsetAsync(cnt, 0, (size_t)N_NODES * 4, stream);
        count_dst_kernel<<<(N_EDGES + 255) / 256, 256, 0, stream>>>(ei, cnt);
        scan_kernel<<<1, 1024, 0, stream>>>(cnt, offs, cursor);
        permute_kernel<<<(N_EDGES + 255) / 256, 256, 0, stream>>>(ei, et, cursor, perm);
        xconv_kernel<<<(N_NODES * CH / 8 + 255) / 256, 256, 0, stream>>>(x, xb);
        bconv_kernel<<<(9 * 2048 + 255) / 256, 256, 0, stream>>>(root, W, Bsw);
        aggregate_kernel<<<(N_NODES * 64 + 255) / 256, 256, 0, stream>>>(
            offs, perm, x, (uint32_t*)sums);
        gemm_fused<<<N_PAD / 128, 256, 0, stream>>>(xb, sums, Bsw, bias, out);
    } else if (ws_size >= cnt_rsv + sums51) {
        // round-1 path: per-relation scatter + GEMM
        int*   cnt  = (int*)d_ws;
        float* sums = (float*)((char*)d_ws + cnt_rsv);
        hipMemsetAsync(cnt, 0, cnt_bytes, stream);
        count_rd_kernel<<<(N_EDGES + 255) / 256, 256, 0, stream>>>(ei, et, cnt);
        gemm_kernel<<<512, 256, 0, stream>>>(x, root, bias, nullptr, out, 0);
        for (int r = 0; r < N_REL; ++r) {
            hipMemsetAsync(sums, 0, sums51, stream);
            scatter_kernel<<<6400, 256, 0, stream>>>(ei, et, x, sums, r);
            gemm_kernel<<<512, 256, 0, stream>>>(sums, W + (size_t)r * CH * CH,
                                                 nullptr, cnt + (size_t)r * N_NODES, out, 1);
        }
    } else {
        int* cnt = (int*)d_ws;
        hipMemsetAsync(cnt, 0, cnt_bytes, stream);
        count_rd_kernel<<<(N_EDGES + 255) / 256, 256, 0, stream>>>(ei, et, cnt);
        gemm_kernel<<<512, 256, 0, stream>>>(x, root, bias, nullptr, out, 0);
        edge_transform_kernel<<<65536, CH, 0, stream>>>(ei, et, x, W, cnt, out);
    }
}

// Round 3
// 627.366 us; speedup vs baseline: 5.6739x; 1.3870x over previous
//
#include <hip/hip_runtime.h>
#include <hip/hip_bf16.h>
#include <stdint.h>

#define N_NODES 100000
#define N_EDGES 1600000
#define CH 128
#define N_REL 8
#define N_PAD 100096   // N_NODES rounded up to multiple of 128 (GEMM strip pad)

#define SCAN_BLOCKS 98          // ceil(N_NODES / 1024)

using frag_ab = __attribute__((ext_vector_type(8))) short;  // 8 bf16
using frag_cd = __attribute__((ext_vector_type(4))) float;  // 4 fp32

__device__ __forceinline__ short f2bs(float f) {
    union { __hip_bfloat16 h; short s; } u;
    u.h = __float2bfloat16(f);
    return u.s;
}

__device__ __forceinline__ uint32_t pack2bf(float a, float b) {
    union { __hip_bfloat16 h; unsigned short s; } ua, ub;
    ua.h = __float2bfloat16(a); ub.h = __float2bfloat16(b);
    return (uint32_t)ua.s | ((uint32_t)ub.s << 16);
}

// ======================= FAST PATH (CSR, no value atomics) =======================

// count edges per dst
__global__ void count_dst_kernel(const int* __restrict__ ei, int* __restrict__ cnt) {
    int e = blockIdx.x * 256 + threadIdx.x;
    if (e < N_EDGES) atomicAdd(&cnt[ei[N_EDGES + e]], 1);
}

// --- two-level scan: 98 blocks x 1024 elements ---
__global__ void scan1_kernel(const int* __restrict__ cnt, int* __restrict__ bsum) {
    __shared__ int sh[256];
    const int t = threadIdx.x;
    const int base = blockIdx.x * 1024 + t * 4;
    int s = 0;
    if (base + 3 < N_NODES) {
        int4 v = *(const int4*)(cnt + base);
        s = v.x + v.y + v.z + v.w;
    } else {
        for (int i = 0; i < 4; ++i) if (base + i < N_NODES) s += cnt[base + i];
    }
    sh[t] = s;
    __syncthreads();
    for (int st = 128; st > 0; st >>= 1) {
        if (t < st) sh[t] += sh[t + st];
        __syncthreads();
    }
    if (t == 0) bsum[blockIdx.x] = sh[0];
}

// exclusive scan of the 98 block sums (in place), one tiny block
__global__ void scan2_kernel(int* __restrict__ bsum) {
    __shared__ int sh[128];
    const int t = threadIdx.x;
    int v = (t < SCAN_BLOCKS) ? bsum[t] : 0;
    sh[t] = v;
    __syncthreads();
    for (int s = 1; s < 128; s <<= 1) {
        int u = (t >= s) ? sh[t - s] : 0;
        __syncthreads();
        sh[t] += u;
        __syncthreads();
    }
    if (t < SCAN_BLOCKS) bsum[t] = sh[t] - v;   // exclusive
}

__global__ void scan3_kernel(const int* __restrict__ cnt, const int* __restrict__ bsum,
                             int* __restrict__ offs, int* __restrict__ cursor) {
    __shared__ int sh[256];
    const int t = threadIdx.x;
    const int base = blockIdx.x * 1024 + t * 4;
    int4 v = make_int4(0, 0, 0, 0);
    if (base + 3 < N_NODES) {
        v = *(const int4*)(cnt + base);
    } else {
        if (base + 0 < N_NODES) v.x = cnt[base + 0];
        if (base + 1 < N_NODES) v.y = cnt[base + 1];
        if (base + 2 < N_NODES) v.z = cnt[base + 2];
        if (base + 3 < N_NODES) v.w = cnt[base + 3];
    }
    const int s = v.x + v.y + v.z + v.w;
    sh[t] = s;
    __syncthreads();
    for (int st = 1; st < 256; st <<= 1) {      // Hillis-Steele inclusive
        int u = (t >= st) ? sh[t - st] : 0;
        __syncthreads();
        sh[t] += u;
        __syncthreads();
    }
    int run = bsum[blockIdx.x] + sh[t] - s;     // exclusive prefix for this thread
    const int o0 = run;
    const int o1 = o0 + v.x;
    const int o2 = o1 + v.y;
    const int o3 = o2 + v.z;
    if (base + 0 < N_NODES) { offs[base + 0] = o0; cursor[base + 0] = o0; }
    if (base + 1 < N_NODES) { offs[base + 1] = o1; cursor[base + 1] = o1; }
    if (base + 2 < N_NODES) { offs[base + 2] = o2; cursor[base + 2] = o2; }
    if (base + 3 < N_NODES) { offs[base + 3] = o3; cursor[base + 3] = o3; }
    if (blockIdx.x == 0 && t == 0) offs[N_NODES] = N_EDGES;
}

// scatter edge (src, rel) packed into dst-sorted slots
__global__ void permute_kernel(const int* __restrict__ ei, const int* __restrict__ et,
                               int* __restrict__ cursor, int* __restrict__ perm) {
    int e = blockIdx.x * 256 + threadIdx.x;
    if (e < N_EDGES) {
        int dst = ei[N_EDGES + e];
        int src = ei[e];
        int r = et[e];
        int pos = atomicAdd(&cursor[dst], 1);
        perm[pos] = src | (r << 17);   // N_NODES < 2^17
    }
}

// wave per dst: gather x[src], per-relation fp32 sums + local counts, write bf16 means.
// sums layout: [rel][N_PAD][128] bf16
__global__ __launch_bounds__(256)
void aggregate_kernel(const int* __restrict__ offs, const int* __restrict__ perm,
                      const float* __restrict__ x, uint32_t* __restrict__ sums_u32) {
    const int dst = (blockIdx.x * 256 + threadIdx.x) >> 6;
    if (dst >= N_NODES) return;
    const int lane = threadIdx.x & 63;

    float2 acc[N_REL];
    int cr[N_REL];
#pragma unroll
    for (int r = 0; r < N_REL; ++r) { acc[r].x = 0.f; acc[r].y = 0.f; cr[r] = 0; }

    const int s = offs[dst], e = offs[dst + 1];
    for (int k = s; k < e; ++k) {
        int p = perm[k];                 // lane-uniform broadcast load
        int src = p & 0x1FFFF;
        int r = p >> 17;
        float2 v = *(const float2*)(x + (size_t)src * CH + lane * 2);
        switch (r) {                     // r is wave-uniform -> uniform branch
            case 0: acc[0].x += v.x; acc[0].y += v.y; cr[0]++; break;
            case 1: acc[1].x += v.x; acc[1].y += v.y; cr[1]++; break;
            case 2: acc[2].x += v.x; acc[2].y += v.y; cr[2]++; break;
            case 3: acc[3].x += v.x; acc[3].y += v.y; cr[3]++; break;
            case 4: acc[4].x += v.x; acc[4].y += v.y; cr[4]++; break;
            case 5: acc[5].x += v.x; acc[5].y += v.y; cr[5]++; break;
            case 6: acc[6].x += v.x; acc[6].y += v.y; cr[6]++; break;
            default: acc[7].x += v.x; acc[7].y += v.y; cr[7]++; break;
        }
    }
#pragma unroll
    for (int r = 0; r < N_REL; ++r) {
        float sc = (cr[r] > 1) ? (1.0f / (float)cr[r]) : 1.0f;
        sums_u32[((size_t)r * N_PAD + dst) * 64 + lane] = pack2bf(acc[r].x * sc, acc[r].y * sc);
    }
}

// x fp32 -> bf16 (flat copy of N*128 elements)
__global__ void xconv_kernel(const float* __restrict__ x, short* __restrict__ xb) {
    int g = blockIdx.x * 256 + threadIdx.x;       // one per 8 elements
    if (g >= N_NODES * CH / 8) return;
    const float4* xp = (const float4*)x;
    float4 a = xp[(size_t)g * 2], b = xp[(size_t)g * 2 + 1];
    frag_ab f;
    f[0] = f2bs(a.x); f[1] = f2bs(a.y); f[2] = f2bs(a.z); f[3] = f2bs(a.w);
    f[4] = f2bs(b.x); f[5] = f2bs(b.y); f[6] = f2bs(b.z); f[7] = f2bs(b.w);
    *(frag_ab*)(xb + (size_t)g * 8) = f;
}

// build swizzled bf16 B: Bsw[chunk][entry][8], entry = ((ks*4+quad)*8+ct)*16+m16
// chunk 0 = root, chunk c>=1 = W[c-1]; frag j -> B[ks*32+quad*8+j][ct*16+m16]
__global__ void bconv_kernel(const float* __restrict__ root, const float* __restrict__ W,
                             short* __restrict__ Bsw) {
    int g = blockIdx.x * 256 + threadIdx.x;
    if (g >= 9 * 2048) return;
    int chunk = g >> 11, entry = g & 2047;
    int m16 = entry & 15, ct = (entry >> 4) & 7, quad = (entry >> 7) & 3, ks = entry >> 9;
    const float* src = (chunk == 0) ? root : W + (size_t)(chunk - 1) * CH * CH;
    int col = ct * 16 + m16, kb = ks * 32 + quad * 8;
    frag_ab f;
#pragma unroll
    for (int j = 0; j < 8; ++j) f[j] = f2bs(src[(size_t)(kb + j) * CH + col]);
    *(frag_ab*)(Bsw + (size_t)g * 8) = f;
}

// out[N,128] = [x | mean_r] @ [root; W_0..W_7] + bias   (K = 1152 = 9 chunks of 128)
// block = 128 rows x 128 cols; 4 waves in 2x2 (each 64x64); B chunk staged in LDS.
__global__ __launch_bounds__(256, 2)
void gemm_fused(const short* __restrict__ xb, const short* __restrict__ sums,
                const short* __restrict__ Bsw, const float* __restrict__ bias,
                float* __restrict__ out) {
    __shared__ short bsh[2048 * 8];   // 32 KB
    const int tid = threadIdx.x;
    const int wave = tid >> 6, lane = tid & 63;
    const int m16 = lane & 15, quad = lane >> 4;
    const int wrow = wave >> 1, wcol = wave & 1;
    const long rowbase = (long)blockIdx.x * 128 + wrow * 64;

    float bcol[4];
#pragma unroll
    for (int ct = 0; ct < 4; ++ct) bcol[ct] = bias[wcol * 64 + ct * 16 + m16];

    frag_cd acc[4][4];
#pragma unroll
    for (int mt = 0; mt < 4; ++mt)
#pragma unroll
        for (int ct = 0; ct < 4; ++ct) acc[mt][ct] = (frag_cd){0.f, 0.f, 0.f, 0.f};

    for (int chunk = 0; chunk < 9; ++chunk) {
        __syncthreads();
        {   // stage 32 KB B chunk: 2048 float4s, 8 per thread, contiguous
            const float4* src = (const float4*)(Bsw + (size_t)chunk * 2048 * 8);
            float4* dst = (float4*)bsh;
#pragma unroll
            for (int i = 0; i < 8; ++i) dst[tid + 256 * i] = src[tid + 256 * i];
        }
        __syncthreads();
        const short* ab = (chunk == 0) ? xb : sums + (size_t)(chunk - 1) * N_PAD * CH;
#pragma unroll
        for (int ks = 0; ks < 4; ++ks) {
            frag_ab af[4];
#pragma unroll
            for (int mt = 0; mt < 4; ++mt)
                af[mt] = *(const frag_ab*)(ab + (rowbase + mt * 16 + m16) * CH + ks * 32 + quad * 8);
#pragma unroll
            for (int ct = 0; ct < 4; ++ct) {
                frag_ab bf = *(const frag_ab*)(bsh + ((((ks * 4 + quad) * 8) + wcol * 4 + ct) * 16 + m16) * 8);
#pragma unroll
                for (int mt = 0; mt < 4; ++mt)
                    acc[mt][ct] = __builtin_amdgcn_mfma_f32_16x16x32_bf16(af[mt], bf, acc[mt][ct], 0, 0, 0);
            }
        }
    }
    // D layout: row = quad*4 + rg, col = m16 (per 16x16 tile)
#pragma unroll
    for (int mt = 0; mt < 4; ++mt) {
#pragma unroll
        for (int ct = 0; ct < 4; ++ct) {
            const long row0 = rowbase + mt * 16 + quad * 4;
            const int col = wcol * 64 + ct * 16 + m16;
#pragma unroll
            for (int rg = 0; rg < 4; ++rg) {
                long r = row0 + rg;
                if (r < N_NODES) out[r * CH + col] = acc[mt][ct][rg] + bcol[ct];
            }
        }
    }
}

// ======================= FALLBACK PATHS (round-1 code) =======================

__global__ void count_rd_kernel(const int* __restrict__ ei, const int* __restrict__ et,
                                int* __restrict__ cnt) {
    int e = blockIdx.x * 256 + threadIdx.x;
    if (e < N_EDGES) {
        int dst = ei[N_EDGES + e];
        int r = et[e];
        atomicAdd(&cnt[r * N_NODES + dst], 1);
    }
}

__global__ void scatter_kernel(const int* __restrict__ ei, const int* __restrict__ et,
                               const float* __restrict__ x, float* __restrict__ sums,
                               int rel) {
    int gid = (blockIdx.x * 256 + threadIdx.x) >> 5;
    int lane = threadIdx.x & 31;
    int ngroups = gridDim.x * 8;
    for (int e = gid; e < N_EDGES; e += ngroups) {
        if (et[e] != rel) continue;
        int src = ei[e];
        int dst = ei[N_EDGES + e];
        float4 v = ((const float4*)(x + (size_t)src * CH))[lane];
        float* s = sums + (size_t)dst * CH + (size_t)lane * 4;
        atomicAdd(s + 0, v.x);
        atomicAdd(s + 1, v.y);
        atomicAdd(s + 2, v.z);
        atomicAdd(s + 3, v.w);
    }
}

__global__ __launch_bounds__(256, 2)
void gemm_kernel(const float* __restrict__ A, const float* __restrict__ B,
                 const float* __restrict__ bias, const int* __restrict__ cnt,
                 float* __restrict__ out, int accumulate) {
    const int wave = threadIdx.x >> 6;
    const int lane = threadIdx.x & 63;
    const int m16 = lane & 15;
    const int quad = lane >> 4;

    frag_ab bfrag[4][8];
#pragma unroll
    for (int ks = 0; ks < 4; ++ks) {
        const int kb = ks * 32 + quad * 8;
#pragma unroll
        for (int ct = 0; ct < 8; ++ct) {
            const int col = ct * 16 + m16;
            frag_ab f;
#pragma unroll
            for (int j = 0; j < 8; ++j)
                f[j] = f2bs(B[(size_t)(kb + j) * CH + col]);
            bfrag[ks][ct] = f;
        }
    }

    const int nstrips = (N_NODES + 63) / 64;
    for (int strip = blockIdx.x; strip < nstrips; strip += gridDim.x) {
        const int row = strip * 64 + wave * 16 + m16;
        const bool valid = row < N_NODES;
        float scale = 1.0f;
        if (cnt != nullptr && valid) {
            int c = cnt[row];
            if (c > 1) scale = 1.0f / (float)c;
        }
        const float4* arow = (const float4*)(A + (size_t)(valid ? row : 0) * CH);
        frag_cd acc[8];
#pragma unroll
        for (int ct = 0; ct < 8; ++ct) acc[ct] = (frag_cd){0.f, 0.f, 0.f, 0.f};
#pragma unroll
        for (int ks = 0; ks < 4; ++ks) {
            float4 a0 = arow[ks * 8 + quad * 2];
            float4 a1 = arow[ks * 8 + quad * 2 + 1];
            frag_ab af;
            af[0] = f2bs(a0.x * scale); af[1] = f2bs(a0.y * scale);
            af[2] = f2bs(a0.z * scale); af[3] = f2bs(a0.w * scale);
            af[4] = f2bs(a1.x * scale); af[5] = f2bs(a1.y * scale);
            af[6] = f2bs(a1.z * scale); af[7] = f2bs(a1.w * scale);
#pragma unroll
            for (int ct = 0; ct < 8; ++ct)
                acc[ct] = __builtin_amdgcn_mfma_f32_16x16x32_bf16(af, bfrag[ks][ct], acc[ct], 0, 0, 0);
        }
        const int obase = strip * 64 + wave * 16 + quad * 4;
#pragma unroll
        for (int ct = 0; ct < 8; ++ct) {
            const int col = ct * 16 + m16;
#pragma unroll
            for (int rg = 0; rg < 4; ++rg) {
                const int r = obase + rg;
                if (r < N_NODES) {
                    const size_t idx = (size_t)r * CH + col;
                    if (accumulate) out[idx] += acc[ct][rg];
                    else out[idx] = acc[ct][rg] + bias[col];
                }
            }
        }
    }
}

__global__ void edge_transform_kernel(const int* __restrict__ ei, const int* __restrict__ et,
                                      const float* __restrict__ x, const float* __restrict__ W,
                                      const int* __restrict__ cnt, float* __restrict__ out) {
    __shared__ float xs[CH];
    const int tid = threadIdx.x;
    for (int e = blockIdx.x; e < N_EDGES; e += gridDim.x) {
        const int src = ei[e];
        const int dst = ei[N_EDGES + e];
        const int r = et[e];
        __syncthreads();
        xs[tid] = x[(size_t)src * CH + tid];
        __syncthreads();
        const int c = cnt[r * N_NODES + dst];
        const float scale = (c > 1) ? (1.0f / (float)c) : 1.0f;
        const float* Wr = W + (size_t)r * CH * CH;
        float acc = 0.f;
#pragma unroll 8
        for (int k = 0; k < CH; ++k) acc += xs[k] * Wr[(size_t)k * CH + tid];
        atomicAdd(&out[(size_t)dst * CH + tid], acc * scale);
    }
}

// ======================= launch =======================

static inline size_t al512(size_t x) { return (x + 511) & ~(size_t)511; }

extern "C" void kernel_launch(void* const* d_in, const int* in_sizes, int n_in,
                              void* d_out, int out_size, void* d_ws, size_t ws_size,
                              hipStream_t stream) {
    const float* x    = (const float*)d_in[0];
    const int*   ei   = (const int*)d_in[1];   // [2, E]: row0=src, row1=dst
    const int*   et   = (const int*)d_in[2];   // [E]
    const float* W    = (const float*)d_in[3]; // [R,128,128]
    const float* root = (const float*)d_in[4]; // [128,128]
    const float* bias = (const float*)d_in[5]; // [128]
    float* out = (float*)d_out;

    // ---- fast-path workspace layout ----
    size_t o = 0;
    const size_t o_cnt  = o; o += al512((size_t)N_NODES * 4);
    const size_t o_offs = o; o += al512((size_t)(N_NODES + 1) * 4);
    const size_t o_cur  = o; o += al512((size_t)N_NODES * 4);
    const size_t o_bsum = o; o += al512((size_t)SCAN_BLOCKS * 4);
    const size_t o_perm = o; o += al512((size_t)N_EDGES * 4);
    const size_t o_bsw  = o; o += al512((size_t)9 * 2048 * 16);
    const size_t o_xb   = o; o += al512((size_t)N_PAD * CH * 2);
    const size_t o_sums = o; o += al512((size_t)N_REL * N_PAD * CH * 2);
    const size_t need_fast = o;

    const size_t cnt_bytes  = (size_t)N_REL * N_NODES * sizeof(int);
    const size_t cnt_rsv    = al512(cnt_bytes);
    const size_t sums51     = (size_t)N_NODES * CH * sizeof(float);

    if (ws_size >= need_fast) {
        char* ws = (char*)d_ws;
        int*      cnt    = (int*)(ws + o_cnt);
        int*      offs   = (int*)(ws + o_offs);
        int*      cursor = (int*)(ws + o_cur);
        int*      bsum   = (int*)(ws + o_bsum);
        int*      perm   = (int*)(ws + o_perm);
        short*    Bsw    = (short*)(ws + o_bsw);
        short*    xb     = (short*)(ws + o_xb);
        short*    sums   = (short*)(ws + o_sums);

        hipMemsetAsync(cnt, 0, (size_t)N_NODES * 4, stream);
        count_dst_kernel<<<(N_EDGES + 255) / 256, 256, 0, stream>>>(ei, cnt);
        scan1_kernel<<<SCAN_BLOCKS, 256, 0, stream>>>(cnt, bsum);
        scan2_kernel<<<1, 128, 0, stream>>>(bsum);
        scan3_kernel<<<SCAN_BLOCKS, 256, 0, stream>>>(cnt, bsum, offs, cursor);
        permute_kernel<<<(N_EDGES + 255) / 256, 256, 0, stream>>>(ei, et, cursor, perm);
        xconv_kernel<<<(N_NODES * CH / 8 + 255) / 256, 256, 0, stream>>>(x, xb);
        bconv_kernel<<<(9 * 2048 + 255) / 256, 256, 0, stream>>>(root, W, Bsw);
        aggregate_kernel<<<(N_NODES * 64 + 255) / 256, 256, 0, stream>>>(
            offs, perm, x, (uint32_t*)sums);
        gemm_fused<<<N_PAD / 128, 256, 0, stream>>>(xb, sums, Bsw, bias, out);
    } else if (ws_size >= cnt_rsv + sums51) {
        // round-1 path: per-relation scatter + GEMM
        int*   cnt  = (int*)d_ws;
        float* sums = (float*)((char*)d_ws + cnt_rsv);
        hipMemsetAsync(cnt, 0, cnt_bytes, stream);
        count_rd_kernel<<<(N_EDGES + 255) / 256, 256, 0, stream>>>(ei, et, cnt);
        gemm_kernel<<<512, 256, 0, stream>>>(x, root, bias, nullptr, out, 0);
        for (int r = 0; r < N_REL; ++r) {
            hipMemsetAsync(sums, 0, sums51, stream);
            scatter_kernel<<<6400, 256, 0, stream>>>(ei, et, x, sums, r);
            gemm_kernel<<<512, 256, 0, stream>>>(sums, W + (size_t)r * CH * CH,
                                                 nullptr, cnt + (size_t)r * N_NODES, out, 1);
        }
    } else {
        int* cnt = (int*)d_ws;
        hipMemsetAsync(cnt, 0, cnt_bytes, stream);
        count_rd_kernel<<<(N_EDGES + 255) / 256, 256, 0, stream>>>(ei, et, cnt);
        gemm_kernel<<<512, 256, 0, stream>>>(x, root, bias, nullptr, out, 0);
        edge_transform_kernel<<<65536, CH, 0, stream>>>(ei, et, x, W, cnt, out);
    }
}

// Round 4
// 551.590 us; speedup vs baseline: 6.4533x; 1.1374x over previous
//
#include <hip/hip_runtime.h>
#include <hip/hip_bf16.h>
#include <stdint.h>

#define N_NODES 100000
#define N_EDGES 1600000
#define CH 128
#define N_REL 8
#define N_PAD 100096            // N_NODES rounded up to multiple of 128 (GEMM strip pad)
#define N_KEYS (N_NODES * N_REL)

#define SCAN_BLOCKS_K 782       // ceil(N_KEYS / 1024)
#define SCAN_BLOCKS_D 98        // ceil(N_NODES / 1024)

using frag_ab = __attribute__((ext_vector_type(8))) short;  // 8 bf16
using frag_cd = __attribute__((ext_vector_type(4))) float;  // 4 fp32

__device__ __forceinline__ short f2bs(float f) {
    union { __hip_bfloat16 h; short s; } u;
    u.h = __float2bfloat16(f);
    return u.s;
}

__device__ __forceinline__ uint32_t pack2bf(float a, float b) {
    union { __hip_bfloat16 h; unsigned short s; } ua, ub;
    ua.h = __float2bfloat16(a); ub.h = __float2bfloat16(b);
    return (uint32_t)ua.s | ((uint32_t)ub.s << 16);
}

__device__ __forceinline__ float bf_lo(uint32_t u) { return __uint_as_float(u << 16); }
__device__ __forceinline__ float bf_hi(uint32_t u) { return __uint_as_float(u & 0xffff0000u); }

// ======================= TIER 1: CSR keyed by (dst*8 + rel) =======================

__global__ void count_key_kernel(const int* __restrict__ ei, const int* __restrict__ et,
                                 int* __restrict__ cnt) {
    int e = blockIdx.x * 256 + threadIdx.x;
    if (e < N_EDGES) {
        int dst = ei[N_EDGES + e];
        int r = et[e];
        atomicAdd(&cnt[dst * N_REL + r], 1);
    }
}

// --- generic two-level scan, 1024 elements per block (256 thr x int4) ---
__global__ void scan1_kernel(const int* __restrict__ cnt, int* __restrict__ bsum, int n) {
    __shared__ int sh[256];
    const int t = threadIdx.x;
    const int base = blockIdx.x * 1024 + t * 4;
    int s = 0;
    if (base + 3 < n) {
        int4 v = *(const int4*)(cnt + base);
        s = v.x + v.y + v.z + v.w;
    } else {
        for (int i = 0; i < 4; ++i) if (base + i < n) s += cnt[base + i];
    }
    sh[t] = s;
    __syncthreads();
    for (int st = 128; st > 0; st >>= 1) {
        if (t < st) sh[t] += sh[t + st];
        __syncthreads();
    }
    if (t == 0) bsum[blockIdx.x] = sh[0];
}

// exclusive scan of up to 1024 block sums in place, one block of 1024 threads
__global__ void scan2_kernel(int* __restrict__ bsum, int nb) {
    __shared__ int sh[1024];
    const int t = threadIdx.x;
    int v = (t < nb) ? bsum[t] : 0;
    sh[t] = v;
    __syncthreads();
    for (int s = 1; s < 1024; s <<= 1) {
        int u = (t >= s) ? sh[t - s] : 0;
        __syncthreads();
        sh[t] += u;
        __syncthreads();
    }
    if (t < nb) bsum[t] = sh[t] - v;   // exclusive
}

// in-place: cnt[i] <- exclusive_prefix_sum(cnt)[i]
__global__ void scan3_kernel(int* __restrict__ cnt, const int* __restrict__ bsum, int n) {
    __shared__ int sh[256];
    const int t = threadIdx.x;
    const int base = blockIdx.x * 1024 + t * 4;
    int4 v = make_int4(0, 0, 0, 0);
    if (base + 3 < n) {
        v = *(const int4*)(cnt + base);
    } else {
        if (base + 0 < n) v.x = cnt[base + 0];
        if (base + 1 < n) v.y = cnt[base + 1];
        if (base + 2 < n) v.z = cnt[base + 2];
        if (base + 3 < n) v.w = cnt[base + 3];
    }
    const int s = v.x + v.y + v.z + v.w;
    sh[t] = s;
    __syncthreads();
    for (int st = 1; st < 256; st <<= 1) {      // Hillis-Steele inclusive
        int u = (t >= st) ? sh[t - st] : 0;
        __syncthreads();
        sh[t] += u;
        __syncthreads();
    }
    int run = bsum[blockIdx.x] + sh[t] - s;     // exclusive prefix for this thread
    const int o0 = run, o1 = o0 + v.x, o2 = o1 + v.y, o3 = o2 + v.z;
    if (base + 3 < n) {
        *(int4*)(cnt + base) = make_int4(o0, o1, o2, o3);
    } else {
        if (base + 0 < n) cnt[base + 0] = o0;
        if (base + 1 < n) cnt[base + 1] = o1;
        if (base + 2 < n) cnt[base + 2] = o2;
        if (base + 3 < n) cnt[base + 3] = o3;
    }
}

// scatter src into (dst,rel)-sorted slots; offs[] doubles as cursor and ends as segment-END
__global__ void permute_key_kernel(const int* __restrict__ ei, const int* __restrict__ et,
                                   int* __restrict__ offs, int* __restrict__ perm) {
    int e = blockIdx.x * 256 + threadIdx.x;
    if (e < N_EDGES) {
        int dst = ei[N_EDGES + e];
        int src = ei[e];
        int r = et[e];
        int pos = atomicAdd(&offs[dst * N_REL + r], 1);
        perm[pos] = src;
    }
}

// sum of xb rows over perm[s..e), dual accumulators for ILP
__device__ __forceinline__ float2 segsum(const int* __restrict__ perm,
                                         const uint32_t* __restrict__ xb32,
                                         int s, int e, int lane) {
    float ax0 = 0.f, ay0 = 0.f, ax1 = 0.f, ay1 = 0.f;
    int k = s;
    for (; k + 1 < e; k += 2) {
        int i0 = perm[k], i1 = perm[k + 1];
        uint32_t u0 = xb32[(size_t)i0 * 64 + lane];
        uint32_t u1 = xb32[(size_t)i1 * 64 + lane];
        ax0 += bf_lo(u0); ay0 += bf_hi(u0);
        ax1 += bf_lo(u1); ay1 += bf_hi(u1);
    }
    if (k < e) {
        uint32_t u0 = xb32[(size_t)perm[k] * 64 + lane];
        ax0 += bf_lo(u0); ay0 += bf_hi(u0);
    }
    return make_float2(ax0 + ax1, ay0 + ay1);
}

// one wave per (dst, rel-pair): gather bf16 rows, mean, write bf16
// ends[] = post-permute offs (segment ends); start(key) = ends[key-1] (segments contiguous)
__global__ __launch_bounds__(256)
void aggregate2_kernel(const int* __restrict__ ends, const int* __restrict__ perm,
                       const uint32_t* __restrict__ xb32, uint32_t* __restrict__ sums_u32) {
    const int wid = (blockIdx.x * 256 + threadIdx.x) >> 6;    // [0, N_NODES*4)
    const int lane = threadIdx.x & 63;
    const int dst = wid >> 2;
    if (dst >= N_NODES) return;
    const int r0 = (wid & 3) * 2;
    const int key0 = dst * N_REL + r0;

    const int s0 = (key0 == 0) ? 0 : ends[key0 - 1];
    const int e0 = ends[key0];
    const int e1 = ends[key0 + 1];

    {   // relation r0 over [s0, e0)
        const int c = e0 - s0;
        float2 a = segsum(perm, xb32, s0, e0, lane);
        const float sc = (c > 1) ? (1.0f / (float)c) : 1.0f;
        sums_u32[((size_t)r0 * N_PAD + dst) * 64 + lane] = pack2bf(a.x * sc, a.y * sc);
    }
    {   // relation r0+1 over [e0, e1)
        const int c = e1 - e0;
        float2 a = segsum(perm, xb32, e0, e1, lane);
        const float sc = (c > 1) ? (1.0f / (float)c) : 1.0f;
        sums_u32[((size_t)(r0 + 1) * N_PAD + dst) * 64 + lane] = pack2bf(a.x * sc, a.y * sc);
    }
}

// ======================= shared helpers =======================

// x fp32 -> bf16 (flat copy of N*128 elements)
__global__ void xconv_kernel(const float* __restrict__ x, short* __restrict__ xb) {
    int g = blockIdx.x * 256 + threadIdx.x;       // one per 8 elements
    if (g >= N_NODES * CH / 8) return;
    const float4* xp = (const float4*)x;
    float4 a = xp[(size_t)g * 2], b = xp[(size_t)g * 2 + 1];
    frag_ab f;
    f[0] = f2bs(a.x); f[1] = f2bs(a.y); f[2] = f2bs(a.z); f[3] = f2bs(a.w);
    f[4] = f2bs(b.x); f[5] = f2bs(b.y); f[6] = f2bs(b.z); f[7] = f2bs(b.w);
    *(frag_ab*)(xb + (size_t)g * 8) = f;
}

// build swizzled bf16 B: Bsw[chunk][entry][8], entry = ((ks*4+quad)*8+ct)*16+m16
__global__ void bconv_kernel(const float* __restrict__ root, const float* __restrict__ W,
                             short* __restrict__ Bsw) {
    int g = blockIdx.x * 256 + threadIdx.x;
    if (g >= 9 * 2048) return;
    int chunk = g >> 11, entry = g & 2047;
    int m16 = entry & 15, ct = (entry >> 4) & 7, quad = (entry >> 7) & 3, ks = entry >> 9;
    const float* src = (chunk == 0) ? root : W + (size_t)(chunk - 1) * CH * CH;
    int col = ct * 16 + m16, kb = ks * 32 + quad * 8;
    frag_ab f;
#pragma unroll
    for (int j = 0; j < 8; ++j) f[j] = f2bs(src[(size_t)(kb + j) * CH + col]);
    *(frag_ab*)(Bsw + (size_t)g * 8) = f;
}

// out[N,128] = [x | mean_r] @ [root; W_0..W_7] + bias   (K = 1152 = 9 chunks of 128)
__global__ __launch_bounds__(256, 2)
void gemm_fused(const short* __restrict__ xb, const short* __restrict__ sums,
                const short* __restrict__ Bsw, const float* __restrict__ bias,
                float* __restrict__ out) {
    __shared__ short bsh[2048 * 8];   // 32 KB
    const int tid = threadIdx.x;
    const int wave = tid >> 6, lane = tid & 63;
    const int m16 = lane & 15, quad = lane >> 4;
    const int wrow = wave >> 1, wcol = wave & 1;
    const long rowbase = (long)blockIdx.x * 128 + wrow * 64;

    float bcol[4];
#pragma unroll
    for (int ct = 0; ct < 4; ++ct) bcol[ct] = bias[wcol * 64 + ct * 16 + m16];

    frag_cd acc[4][4];
#pragma unroll
    for (int mt = 0; mt < 4; ++mt)
#pragma unroll
        for (int ct = 0; ct < 4; ++ct) acc[mt][ct] = (frag_cd){0.f, 0.f, 0.f, 0.f};

    for (int chunk = 0; chunk < 9; ++chunk) {
        __syncthreads();
        {   // stage 32 KB B chunk
            const float4* src = (const float4*)(Bsw + (size_t)chunk * 2048 * 8);
            float4* dst = (float4*)bsh;
#pragma unroll
            for (int i = 0; i < 8; ++i) dst[tid + 256 * i] = src[tid + 256 * i];
        }
        __syncthreads();
        const short* ab = (chunk == 0) ? xb : sums + (size_t)(chunk - 1) * N_PAD * CH;
#pragma unroll
        for (int ks = 0; ks < 4; ++ks) {
            frag_ab af[4];
#pragma unroll
            for (int mt = 0; mt < 4; ++mt)
                af[mt] = *(const frag_ab*)(ab + (rowbase + mt * 16 + m16) * CH + ks * 32 + quad * 8);
#pragma unroll
            for (int ct = 0; ct < 4; ++ct) {
                frag_ab bf = *(const frag_ab*)(bsh + ((((ks * 4 + quad) * 8) + wcol * 4 + ct) * 16 + m16) * 8);
#pragma unroll
                for (int mt = 0; mt < 4; ++mt)
                    acc[mt][ct] = __builtin_amdgcn_mfma_f32_16x16x32_bf16(af[mt], bf, acc[mt][ct], 0, 0, 0);
            }
        }
    }
#pragma unroll
    for (int mt = 0; mt < 4; ++mt) {
#pragma unroll
        for (int ct = 0; ct < 4; ++ct) {
            const long row0 = rowbase + mt * 16 + quad * 4;
            const int col = wcol * 64 + ct * 16 + m16;
#pragma unroll
            for (int rg = 0; rg < 4; ++rg) {
                long r = row0 + rg;
                if (r < N_NODES) out[r * CH + col] = acc[mt][ct][rg] + bcol[ct];
            }
        }
    }
}

// ======================= TIER 2: round-3-style (key = dst) =======================

__global__ void count_dst_kernel(const int* __restrict__ ei, int* __restrict__ cnt) {
    int e = blockIdx.x * 256 + threadIdx.x;
    if (e < N_EDGES) atomicAdd(&cnt[ei[N_EDGES + e]], 1);
}

__global__ void permute_dst_kernel(const int* __restrict__ ei, const int* __restrict__ et,
                                   int* __restrict__ offs, int* __restrict__ perm) {
    int e = blockIdx.x * 256 + threadIdx.x;
    if (e < N_EDGES) {
        int dst = ei[N_EDGES + e];
        int src = ei[e];
        int r = et[e];
        int pos = atomicAdd(&offs[dst], 1);
        perm[pos] = src | (r << 17);
    }
}

__global__ __launch_bounds__(256)
void aggregate_mid_kernel(const int* __restrict__ ends, const int* __restrict__ perm,
                          const float* __restrict__ x, uint32_t* __restrict__ sums_u32) {
    const int dst = (blockIdx.x * 256 + threadIdx.x) >> 6;
    if (dst >= N_NODES) return;
    const int lane = threadIdx.x & 63;

    float2 acc[N_REL];
    int cr[N_REL];
#pragma unroll
    for (int r = 0; r < N_REL; ++r) { acc[r].x = 0.f; acc[r].y = 0.f; cr[r] = 0; }

    const int s = (dst == 0) ? 0 : ends[dst - 1], e = ends[dst];
    for (int k = s; k < e; ++k) {
        int p = perm[k];
        int src = p & 0x1FFFF;
        int r = p >> 17;
        float2 v = *(const float2*)(x + (size_t)src * CH + lane * 2);
        switch (r) {
            case 0: acc[0].x += v.x; acc[0].y += v.y; cr[0]++; break;
            case 1: acc[1].x += v.x; acc[1].y += v.y; cr[1]++; break;
            case 2: acc[2].x += v.x; acc[2].y += v.y; cr[2]++; break;
            case 3: acc[3].x += v.x; acc[3].y += v.y; cr[3]++; break;
            case 4: acc[4].x += v.x; acc[4].y += v.y; cr[4]++; break;
            case 5: acc[5].x += v.x; acc[5].y += v.y; cr[5]++; break;
            case 6: acc[6].x += v.x; acc[6].y += v.y; cr[6]++; break;
            default: acc[7].x += v.x; acc[7].y += v.y; cr[7]++; break;
        }
    }
#pragma unroll
    for (int r = 0; r < N_REL; ++r) {
        float sc = (cr[r] > 1) ? (1.0f / (float)cr[r]) : 1.0f;
        sums_u32[((size_t)r * N_PAD + dst) * 64 + lane] = pack2bf(acc[r].x * sc, acc[r].y * sc);
    }
}

// ======================= TIER 3/4 fallbacks (round-1 code) =======================

__global__ void count_rd_kernel(const int* __restrict__ ei, const int* __restrict__ et,
                                int* __restrict__ cnt) {
    int e = blockIdx.x * 256 + threadIdx.x;
    if (e < N_EDGES) {
        int dst = ei[N_EDGES + e];
        int r = et[e];
        atomicAdd(&cnt[r * N_NODES + dst], 1);
    }
}

__global__ void scatter_kernel(const int* __restrict__ ei, const int* __restrict__ et,
                               const float* __restrict__ x, float* __restrict__ sums,
                               int rel) {
    int gid = (blockIdx.x * 256 + threadIdx.x) >> 5;
    int lane = threadIdx.x & 31;
    int ngroups = gridDim.x * 8;
    for (int e = gid; e < N_EDGES; e += ngroups) {
        if (et[e] != rel) continue;
        int src = ei[e];
        int dst = ei[N_EDGES + e];
        float4 v = ((const float4*)(x + (size_t)src * CH))[lane];
        float* s = sums + (size_t)dst * CH + (size_t)lane * 4;
        atomicAdd(s + 0, v.x);
        atomicAdd(s + 1, v.y);
        atomicAdd(s + 2, v.z);
        atomicAdd(s + 3, v.w);
    }
}

__global__ __launch_bounds__(256, 2)
void gemm_kernel(const float* __restrict__ A, const float* __restrict__ B,
                 const float* __restrict__ bias, const int* __restrict__ cnt,
                 float* __restrict__ out, int accumulate) {
    const int wave = threadIdx.x >> 6;
    const int lane = threadIdx.x & 63;
    const int m16 = lane & 15;
    const int quad = lane >> 4;

    frag_ab bfrag[4][8];
#pragma unroll
    for (int ks = 0; ks < 4; ++ks) {
        const int kb = ks * 32 + quad * 8;
#pragma unroll
        for (int ct = 0; ct < 8; ++ct) {
            const int col = ct * 16 + m16;
            frag_ab f;
#pragma unroll
            for (int j = 0; j < 8; ++j)
                f[j] = f2bs(B[(size_t)(kb + j) * CH + col]);
            bfrag[ks][ct] = f;
        }
    }

    const int nstrips = (N_NODES + 63) / 64;
    for (int strip = blockIdx.x; strip < nstrips; strip += gridDim.x) {
        const int row = strip * 64 + wave * 16 + m16;
        const bool valid = row < N_NODES;
        float scale = 1.0f;
        if (cnt != nullptr && valid) {
            int c = cnt[row];
            if (c > 1) scale = 1.0f / (float)c;
        }
        const float4* arow = (const float4*)(A + (size_t)(valid ? row : 0) * CH);
        frag_cd acc[8];
#pragma unroll
        for (int ct = 0; ct < 8; ++ct) acc[ct] = (frag_cd){0.f, 0.f, 0.f, 0.f};
#pragma unroll
        for (int ks = 0; ks < 4; ++ks) {
            float4 a0 = arow[ks * 8 + quad * 2];
            float4 a1 = arow[ks * 8 + quad * 2 + 1];
            frag_ab af;
            af[0] = f2bs(a0.x * scale); af[1] = f2bs(a0.y * scale);
            af[2] = f2bs(a0.z * scale); af[3] = f2bs(a0.w * scale);
            af[4] = f2bs(a1.x * scale); af[5] = f2bs(a1.y * scale);
            af[6] = f2bs(a1.z * scale); af[7] = f2bs(a1.w * scale);
#pragma unroll
            for (int ct = 0; ct < 8; ++ct)
                acc[ct] = __builtin_amdgcn_mfma_f32_16x16x32_bf16(af, bfrag[ks][ct], acc[ct], 0, 0, 0);
        }
        const int obase = strip * 64 + wave * 16 + quad * 4;
#pragma unroll
        for (int ct = 0; ct < 8; ++ct) {
            const int col = ct * 16 + m16;
#pragma unroll
            for (int rg = 0; rg < 4; ++rg) {
                const int r = obase + rg;
                if (r < N_NODES) {
                    const size_t idx = (size_t)r * CH + col;
                    if (accumulate) out[idx] += acc[ct][rg];
                    else out[idx] = acc[ct][rg] + bias[col];
                }
            }
        }
    }
}

__global__ void edge_transform_kernel(const int* __restrict__ ei, const int* __restrict__ et,
                                      const float* __restrict__ x, const float* __restrict__ W,
                                      const int* __restrict__ cnt, float* __restrict__ out) {
    __shared__ float xs[CH];
    const int tid = threadIdx.x;
    for (int e = blockIdx.x; e < N_EDGES; e += gridDim.x) {
        const int src = ei[e];
        const int dst = ei[N_EDGES + e];
        const int r = et[e];
        __syncthreads();
        xs[tid] = x[(size_t)src * CH + tid];
        __syncthreads();
        const int c = cnt[r * N_NODES + dst];
        const float scale = (c > 1) ? (1.0f / (float)c) : 1.0f;
        const float* Wr = W + (size_t)r * CH * CH;
        float acc = 0.f;
#pragma unroll 8
        for (int k = 0; k < CH; ++k) acc += xs[k] * Wr[(size_t)k * CH + tid];
        atomicAdd(&out[(size_t)dst * CH + tid], acc * scale);
    }
}

// ======================= launch =======================

static inline size_t al512(size_t x) { return (x + 511) & ~(size_t)511; }

extern "C" void kernel_launch(void* const* d_in, const int* in_sizes, int n_in,
                              void* d_out, int out_size, void* d_ws, size_t ws_size,
                              hipStream_t stream) {
    const float* x    = (const float*)d_in[0];
    const int*   ei   = (const int*)d_in[1];   // [2, E]: row0=src, row1=dst
    const int*   et   = (const int*)d_in[2];   // [E]
    const float* W    = (const float*)d_in[3]; // [R,128,128]
    const float* root = (const float*)d_in[4]; // [128,128]
    const float* bias = (const float*)d_in[5]; // [128]
    float* out = (float*)d_out;

    // ---- tier-1 workspace layout (key = dst*8+rel) ----
    size_t o = 0;
    const size_t o_cnt  = o; o += al512((size_t)N_KEYS * 4);         // offs/ends in place
    const size_t o_bsum = o; o += al512((size_t)SCAN_BLOCKS_K * 4);
    const size_t o_perm = o; o += al512((size_t)N_EDGES * 4);
    const size_t o_bsw  = o; o += al512((size_t)9 * 2048 * 16);
    const size_t o_xb   = o; o += al512((size_t)N_PAD * CH * 2);
    const size_t o_sums = o; o += al512((size_t)N_REL * N_PAD * CH * 2);
    const size_t need_t1 = o;

    // ---- tier-2 layout (key = dst) ----
    size_t p = 0;
    const size_t p_cnt  = p; p += al512((size_t)N_NODES * 4);
    const size_t p_bsum = p; p += al512((size_t)SCAN_BLOCKS_D * 4);
    const size_t p_perm = p; p += al512((size_t)N_EDGES * 4);
    const size_t p_bsw  = p; p += al512((size_t)9 * 2048 * 16);
    const size_t p_xb   = p; p += al512((size_t)N_PAD * CH * 2);
    const size_t p_sums = p; p += al512((size_t)N_REL * N_PAD * CH * 2);
    const size_t need_t2 = p;

    const size_t cnt_bytes = (size_t)N_REL * N_NODES * sizeof(int);
    const size_t cnt_rsv   = al512(cnt_bytes);
    const size_t sums51    = (size_t)N_NODES * CH * sizeof(float);

    char* ws = (char*)d_ws;
    if (ws_size >= need_t1) {
        int*   cnt  = (int*)(ws + o_cnt);
        int*   bsum = (int*)(ws + o_bsum);
        int*   perm = (int*)(ws + o_perm);
        short* Bsw  = (short*)(ws + o_bsw);
        short* xb   = (short*)(ws + o_xb);
        short* sums = (short*)(ws + o_sums);

        hipMemsetAsync(cnt, 0, (size_t)N_KEYS * 4, stream);
        count_key_kernel<<<(N_EDGES + 255) / 256, 256, 0, stream>>>(ei, et, cnt);
        scan1_kernel<<<SCAN_BLOCKS_K, 256, 0, stream>>>(cnt, bsum, N_KEYS);
        scan2_kernel<<<1, 1024, 0, stream>>>(bsum, SCAN_BLOCKS_K);
        scan3_kernel<<<SCAN_BLOCKS_K, 256, 0, stream>>>(cnt, bsum, N_KEYS);
        permute_key_kernel<<<(N_EDGES + 255) / 256, 256, 0, stream>>>(ei, et, cnt, perm);
        xconv_kernel<<<(N_NODES * CH / 8 + 255) / 256, 256, 0, stream>>>(x, xb);
        bconv_kernel<<<(9 * 2048 + 255) / 256, 256, 0, stream>>>(root, W, Bsw);
        aggregate2_kernel<<<(N_NODES * 4 * 64) / 256, 256, 0, stream>>>(
            cnt, perm, (const uint32_t*)xb, (uint32_t*)sums);
        gemm_fused<<<N_PAD / 128, 256, 0, stream>>>(xb, sums, Bsw, bias, out);
    } else if (ws_size >= need_t2) {
        int*   cnt  = (int*)(ws + p_cnt);
        int*   bsum = (int*)(ws + p_bsum);
        int*   perm = (int*)(ws + p_perm);
        short* Bsw  = (short*)(ws + p_bsw);
        short* xb   = (short*)(ws + p_xb);
        short* sums = (short*)(ws + p_sums);

        hipMemsetAsync(cnt, 0, (size_t)N_NODES * 4, stream);
        count_dst_kernel<<<(N_EDGES + 255) / 256, 256, 0, stream>>>(ei, cnt);
        scan1_kernel<<<SCAN_BLOCKS_D, 256, 0, stream>>>(cnt, bsum, N_NODES);
        scan2_kernel<<<1, 1024, 0, stream>>>(bsum, SCAN_BLOCKS_D);
        scan3_kernel<<<SCAN_BLOCKS_D, 256, 0, stream>>>(cnt, bsum, N_NODES);
        permute_dst_kernel<<<(N_EDGES + 255) / 256, 256, 0, stream>>>(ei, et, cnt, perm);
        xconv_kernel<<<(N_NODES * CH / 8 + 255) / 256, 256, 0, stream>>>(x, xb);
        bconv_kernel<<<(9 * 2048 + 255) / 256, 256, 0, stream>>>(root, W, Bsw);
        aggregate_mid_kernel<<<(N_NODES * 64 + 255) / 256, 256, 0, stream>>>(
            cnt, perm, x, (uint32_t*)sums);
        gemm_fused<<<N_PAD / 128, 256, 0, stream>>>(xb, sums, Bsw, bias, out);
    } else if (ws_size >= cnt_rsv + sums51) {
        int*   cnt  = (int*)d_ws;
        float* sums = (float*)((char*)d_ws + cnt_rsv);
        hipMemsetAsync(cnt, 0, cnt_bytes, stream);
        count_rd_kernel<<<(N_EDGES + 255) / 256, 256, 0, stream>>>(ei, et, cnt);
        gemm_kernel<<<512, 256, 0, stream>>>(x, root, bias, nullptr, out, 0);
        for (int r = 0; r < N_REL; ++r) {
            hipMemsetAsync(sums, 0, sums51, stream);
            scatter_kernel<<<6400, 256, 0, stream>>>(ei, et, x, sums, r);
            gemm_kernel<<<512, 256, 0, stream>>>(sums, W + (size_t)r * CH * CH,
                                                 nullptr, cnt + (size_t)r * N_NODES, out, 1);
        }
    } else {
        int* cnt = (int*)d_ws;
        hipMemsetAsync(cnt, 0, cnt_bytes, stream);
        count_rd_kernel<<<(N_EDGES + 255) / 256, 256, 0, stream>>>(ei, et, cnt);
        gemm_kernel<<<512, 256, 0, stream>>>(x, root, bias, nullptr, out, 0);
        edge_transform_kernel<<<65536, CH, 0, stream>>>(ei, et, x, W, cnt, out);
    }
}